// Round 10
// baseline (3055.626 us; speedup 1.0000x reference)
//
#include <hip/hip_runtime.h>
#include <hip/hip_bf16.h>

typedef unsigned short u16;
typedef unsigned int u32;
typedef unsigned long long u64;
typedef short  s16x8 __attribute__((ext_vector_type(8)));
typedef float  f32x4 __attribute__((ext_vector_type(4)));
typedef u32    u32x4 __attribute__((ext_vector_type(4)));

#define T_STEPS 512
#define BATCH   32
#define HID     512
#define EMBD    300
#define NGATE   2048
#define NWG     16

// ---- workspace layout (bytes) ----
#define XZ_OFF   0ull
#define XZ_BYTES (512ull*32*2048*4)          // 134,217,728  f32 [t][b][wg16][g][32]
#define UB_OFF   (XZ_OFF + XZ_BYTES)
#define UB_BYTES (2048ull*512*2)             // 16 per-WG U images (128 cols, bf16, swizzled)
#define WT_OFF   (UB_OFF + UB_BYTES)
#define WT_BYTES (2048ull*320*2)             // W^T bf16 swizzled
#define HB_OFF   (WT_OFF + WT_BYTES)
#define HB_BYTES (2ull*8192*4)               // 2 slots x 8192 u32 of LSB-tagged bf16 pairs

__device__ inline u16 f2b(float f) {
  u32 u = __builtin_bit_cast(u32, f);
  return (u16)((u + 0x7fffu + ((u >> 16) & 1u)) >> 16);
}

__device__ inline void st32_agent(u32* p, u32 v) {
  __hip_atomic_store(p, v, __ATOMIC_RELAXED, __HIP_MEMORY_SCOPE_AGENT);
}

// ---------- pack W: [300][2048] f32 -> wt[n][kpad=320] bf16 swizzled ----------
__global__ __launch_bounds__(64) void pack_w(const float* __restrict__ W, u16* __restrict__ wt) {
  int n = blockIdx.x;
  for (int i = 0; i < 5; ++i) {
    int k = i * 64 + threadIdx.x;
    float v = (k < EMBD) ? W[(size_t)k * NGATE + n] : 0.f;
    u32 off = ((u32)(2 * k)) ^ (((u32)(n & 7)) << 4);
    *(u16*)((char*)wt + (size_t)n * 640 + off) = f2b(v);
  }
}

// ---------- pack U: 16 per-WG images, 128 cols each, col-major swizzled bf16 ----------
// WG w (0..15) owns local cols nl=0..127: gate g = nl&3, h-col j = w*32 + (nl>>2)
__global__ __launch_bounds__(64) void pack_u(const float* __restrict__ U, u16* __restrict__ ub) {
  int blk = blockIdx.x;             // = w*128 + nl
  int w = blk >> 7, nl = blk & 127;
  int gcol = (nl & 3) * 512 + w * 32 + (nl >> 2);
  for (int i = 0; i < 8; ++i) {
    int k = i * 64 + threadIdx.x;
    float v = U[(size_t)k * NGATE + gcol];
    u32 off = ((u32)(2 * k)) ^ (((u32)(nl & 7)) << 4);
    *(u16*)((char*)ub + (size_t)blk * 1024 + off) = f2b(v);
  }
}

// ---------- phase 1: xz = emb[tok] @ W + bias, layout [t][b][wg16][g][32] ----------
__global__ __launch_bounds__(256) void xz_gemm(const int* __restrict__ tokens,
                                               const float* __restrict__ emb,
                                               const u16* __restrict__ wt,
                                               const float* __restrict__ bias,
                                               float* __restrict__ xz) {
  extern __shared__ char smem[];
  const int tid = threadIdx.x;
  const int lane = tid & 63, wv = tid >> 6;
  const int m0 = (blockIdx.x >> 5) * 64;
  const int n0 = (blockIdx.x & 31) * 64;

  { // stage A: 64 emb rows gathered, f32 -> bf16
    int row = tid >> 2, q = tid & 3;
    int tok = tokens[m0 + row];
    const float* er = emb + (size_t)tok * EMBD;
    for (int i = 0; i < 10; ++i) {
      int k = q * 80 + i * 8;
      float4 lo = {0, 0, 0, 0}, hi = {0, 0, 0, 0};
      if (k <= 296) lo = *(const float4*)(er + k);
      if (k <= 292) hi = *(const float4*)(er + k + 4);
      u16 u[8] = {f2b(lo.x), f2b(lo.y), f2b(lo.z), f2b(lo.w),
                  f2b(hi.x), f2b(hi.y), f2b(hi.z), f2b(hi.w)};
      int kc = q * 10 + i;
      *(uint4*)(smem + kc * 1040 + row * 16) = *(uint4*)u;
    }
  }
  { // stage B: linear copy of pre-swizzled wt panel
    const uint4* src = (const uint4*)((const char*)wt + (size_t)n0 * 640);
    for (int i = 0; i < 10; ++i)
      *(uint4*)(smem + 41600 + (i * 256 + tid) * 16) = src[i * 256 + tid];
  }
  __syncthreads();

  const int mq = wv >> 1, nq = wv & 1;
  const int arow = lane & 15, kq4 = lane >> 4;
  f32x4 acc[2][2] = {};
#pragma unroll
  for (int ks = 0; ks < 10; ++ks) {
    s16x8 af[2], bfr[2];
#pragma unroll
    for (int mt = 0; mt < 2; ++mt) {
      int row = mq * 32 + mt * 16 + arow;
      int kc = ks * 4 + kq4;
      af[mt] = *(const s16x8*)(smem + kc * 1040 + row * 16);
    }
#pragma unroll
    for (int nt = 0; nt < 2; ++nt) {
      int nl = nq * 32 + nt * 16 + arow;
      u32 kb = (u32)(ks * 64 + (kq4 << 4));
      bfr[nt] = *(const s16x8*)(smem + 41600 + nl * 640 + (kb ^ (((u32)(nl & 7)) << 4)));
    }
#pragma unroll
    for (int mt = 0; mt < 2; ++mt)
#pragma unroll
      for (int nt = 0; nt < 2; ++nt)
        acc[mt][nt] = __builtin_amdgcn_mfma_f32_16x16x32_bf16(af[mt], bfr[nt], acc[mt][nt], 0, 0, 0);
  }
#pragma unroll
  for (int mt = 0; mt < 2; ++mt)
#pragma unroll
    for (int nt = 0; nt < 2; ++nt) {
      int gn = n0 + nq * 32 + nt * 16 + arow;
      float bv = bias[gn];
      int g = gn >> 9, j = gn & 511;
      size_t inner = (size_t)((j >> 5) * 128 + g * 32 + (j & 31));
#pragma unroll
      for (int r = 0; r < 4; ++r) {
        int gm = m0 + mq * 32 + mt * 16 + (kq4 << 2) + r;
        int tt = gm & 511, bb = gm >> 9;       // tokens flat = b*T + t
        xz[(size_t)(tt * 32 + bb) * 2048 + inner] = acc[mt][nt][r] + bv;
      }
    }
}

// ---------- phase 2: persistent 16-WG x 512-thread recurrent kernel ----------
// Each WG owns 128 gate-cols (32 h-cols). LDS: U image 128KB + h tile 32KB = 160KB.
// Poll + h-tile fill by all 8 waves (wave l-th load = one full row -> conflict-free
// b128 writes). MFMA+gates+publish by waves 0-3, 32 cols each (2 col-groups reuse
// each h fragment). Swapped-operand MFMA: lane (wv,kq,arow) cg-th acc holds all 4
// gates of cells (b=arow / arow+16, j = wg*32 + wv*8 + cg*4 + kq).
// Sync: LSB-embedded 2-bit tags on every published bf16 pair (round-6 protocol).
__global__ __launch_bounds__(512) void lstm_persist(const float* __restrict__ xz,
                                                    const u16* __restrict__ ub,
                                                    u32* __restrict__ hbuf,
                                                    float* __restrict__ out) {
  extern __shared__ char smem[];
  char* hl = smem + 131072;                  // h tile [32][512] bf16 swizzled, 32KB
  const int tid = threadIdx.x;
  const int lane = tid & 63, wv = tid >> 6;
  const int wg = blockIdx.x;

  { // stage pre-swizzled U slice: 128KB linear copy
    const uint4* src = (const uint4*)(ub + (size_t)wg * 65536);
    uint4* dst = (uint4*)smem;
    for (int i = 0; i < 16; ++i) dst[i * 512 + tid] = src[i * 512 + tid];
  }

  const int arow = lane & 15, kq = lane >> 4;
  const u32 aswz = ((u32)(arow & 7)) << 4;   // also U swizzle (nl&7 == arow&7)
  const bool worker = (wv < 4);
  float cst[2][2] = {{0.f, 0.f}, {0.f, 0.f}};   // [cg][half]

  // poll voffsets: thread covers u32 idx = tid*4 + l*2048 (bytes tid*16 + l*8192)
  const u32 vo0 = (u32)(tid * 16), vo1 = (u32)(tid * 16 + 8192);
  const u32 vo2 = (u32)(tid * 16 + 16384), vo3 = (u32)(tid * 16 + 24576);
  const u32 hcolb = (u32)(lane * 16);        // per-l row = wv + 8l, whole-wave row fill

  // publish: jl(cg) = wv*8 + cg*4 + kq; word pairs (2p,2p+1) via shfl_xor(16)
  const int pb = (kq & 1) ? (arow + 16) : arow;
  const u32 pidx0 = (u32)(pb * 256 + wg * 16 + wv * 4 + (kq >> 1));   // cg=0; cg=1 -> +2

  float xzv[2][2][4];                        // [cg][half][gate]
  if (worker) { // prefetch xz for t=0: addr = (t*32+b)*2048 + wg*128 + g*32 + jl
    const float* p = xz + (size_t)arow * 2048 + wg * 128 + wv * 8 + kq;
#pragma unroll
    for (int cg = 0; cg < 2; ++cg)
#pragma unroll
      for (int g = 0; g < 4; ++g) {
        xzv[cg][0][g] = p[g * 32 + cg * 4];
        xzv[cg][1][g] = p[16 * 2048 + g * 32 + cg * 4];
      }
  }
  __syncthreads();   // U staged

  for (int t = 0; t < T_STEPS; ++t) {
    if (t > 0) {
      // ---- poll-copy h_t from MALL into LDS (tags embedded in bf16 LSBs) ----
      u32 tg = (((u32)t >> 1) + 1u) & 3u;
      u32 pat = (tg & 1u) | ((tg >> 1) << 16);
      const u64 sb = (u64)(uintptr_t)hbuf + (u64)((t & 1) * 32768);
      u32x4 q0, q1, q2, q3;
      int tries = 0;
      for (;;) {
        asm volatile(
          "global_load_dwordx4 %0, %4, %8 sc0 sc1\n\t"
          "global_load_dwordx4 %1, %5, %8 sc0 sc1\n\t"
          "global_load_dwordx4 %2, %6, %8 sc0 sc1\n\t"
          "global_load_dwordx4 %3, %7, %8 sc0 sc1\n\t"
          "s_waitcnt vmcnt(0)"
          : "=&v"(q0), "=&v"(q1), "=&v"(q2), "=&v"(q3)
          : "v"(vo0), "v"(vo1), "v"(vo2), "v"(vo3), "s"(sb)
          : "memory");
        u32 x0 = (q0.x ^ pat) | (q0.y ^ pat) | (q0.z ^ pat) | (q0.w ^ pat);
        u32 x1 = (q1.x ^ pat) | (q1.y ^ pat) | (q1.z ^ pat) | (q1.w ^ pat);
        u32 x2 = (q2.x ^ pat) | (q2.y ^ pat) | (q2.z ^ pat) | (q2.w ^ pat);
        u32 x3 = (q3.x ^ pat) | (q3.y ^ pat) | (q3.z ^ pat) | (q3.w ^ pat);
        u32 bad = (x0 | x1 | x2 | x3) & 0x00010001u;
        if (bad == 0 || ++tries > 65536) break;   // cap: fail loudly, never hang
        __builtin_amdgcn_s_sleep(1);
      }
#define HW(L, Q) { u32 r_ = (u32)wv + 8u * (L);                                \
        u32 off_ = r_ * 1024u + (hcolb ^ ((r_ & 7u) << 4));                    \
        *(u32x4*)(hl + off_) = (Q); }
      HW(0, q0) HW(1, q1) HW(2, q2) HW(3, q3)
#undef HW
    }
    __syncthreads();   // A: h_lds ready (poll success implies all prior reads done)

    if (worker) {
      f32x4 acc[2][2] = {};                  // [cg][half]
      if (t > 0) {  // z^T = U rows x h: rows=gate-cols, cols=batches
#pragma unroll
        for (int ks = 0; ks < 16; ++ks) {
          u32 kb = (u32)(ks * 64 + (kq << 4));
          s16x8 h0 = *(const s16x8*)(hl + arow * 1024 + (kb ^ aswz));
          s16x8 h1 = *(const s16x8*)(hl + (arow + 16) * 1024 + (kb ^ aswz));
#pragma unroll
          for (int cg = 0; cg < 2; ++cg) {
            int nl = wv * 32 + cg * 16 + arow;
            s16x8 uu = *(const s16x8*)(smem + nl * 1024 + (kb ^ aswz));
            acc[cg][0] = __builtin_amdgcn_mfma_f32_16x16x32_bf16(uu, h0, acc[cg][0], 0, 0, 0);
            acc[cg][1] = __builtin_amdgcn_mfma_f32_16x16x32_bf16(uu, h1, acc[cg][1], 0, 0, 0);
          }
        }
      }

      // gates in-register: acc[cg][e][g] = z[gate g][b], cell (b, wg*32+wv*8+cg*4+kq)
      float hov[2][2], cov[2][2];
#pragma unroll
      for (int cg = 0; cg < 2; ++cg)
#pragma unroll
        for (int e = 0; e < 2; ++e) {
          f32x4 zr = acc[cg][e];
          float zi = zr[0] + xzv[cg][e][0];
          float zf = zr[1] + xzv[cg][e][1];
          float zg = zr[2] + xzv[cg][e][2];
          float zo = zr[3] + xzv[cg][e][3];
          float ig = 1.f / (1.f + __expf(-zi));
          float fg = 1.f / (1.f + __expf(-zf));
          float gg = 1.f - 2.f / (__expf(2.f * zg) + 1.f);
          float og = 1.f / (1.f + __expf(-zo));
          float cc = fg * cst[cg][e] + ig * gg;
          float hh = og * (1.f - 2.f / (__expf(2.f * cc) + 1.f));
          cst[cg][e] = cc;
          hov[cg][e] = hh; cov[cg][e] = cc;
        }

      if (t < T_STEPS - 1) {
        u32 tg2 = (((u32)(t + 1) >> 1) + 1u) & 3u;
        u32 tagbits = (tg2 & 1u) | ((tg2 >> 1) << 16);
        u32* slot = hbuf + (size_t)((t + 1) & 1) * 8192;
#pragma unroll
        for (int cg = 0; cg < 2; ++cg) {
          u32 pk = (u32)f2b(hov[cg][0]) | ((u32)f2b(hov[cg][1]) << 16);
          u32 pr = (u32)__shfl_xor((int)pk, 16, 64);          // partner j = jl^1
          u32 val = (kq & 1) ? ((pr >> 16) | (pk & 0xFFFF0000u))
                             : ((pk & 0xFFFFu) | (pr << 16));
          val = (val & 0xFFFEFFFEu) | tagbits;
          st32_agent(&slot[pidx0 + 2 * cg], val);
        }
        { // prefetch next xz
          const float* p = xz + ((size_t)(t + 1) * 32 + arow) * 2048 + wg * 128 + wv * 8 + kq;
#pragma unroll
          for (int cg = 0; cg < 2; ++cg)
#pragma unroll
            for (int g = 0; g < 4; ++g) {
              xzv[cg][0][g] = p[g * 32 + cg * 4];
              xzv[cg][1][g] = p[16 * 2048 + g * 32 + cg * 4];
            }
        }
      } else {
#pragma unroll
        for (int cg = 0; cg < 2; ++cg) {
          int j = wg * 32 + wv * 8 + cg * 4 + kq;
          out[arow * 512 + j]                 = hov[cg][0];
          out[(arow + 16) * 512 + j]          = hov[cg][1];
          out[16384 + arow * 512 + j]         = cov[cg][0];
          out[16384 + (arow + 16) * 512 + j]  = cov[cg][1];
        }
      }
    }
    // no trailing barrier: a wave's next poll can't succeed until ALL WGs' worker
    // waves published (tags), which happens only after their hl reads completed;
    // barrier A then orders this WG's hl overwrite against its own waves.
  }
}

extern "C" void kernel_launch(void* const* d_in, const int* in_sizes, int n_in,
                              void* d_out, int out_size, void* d_ws, size_t ws_size,
                              hipStream_t stream) {
  const int*   tokens = (const int*)d_in[0];
  const float* emb    = (const float*)d_in[1];
  const float* W      = (const float*)d_in[2];
  const float* U      = (const float*)d_in[3];
  const float* bias   = (const float*)d_in[4];
  float* out = (float*)d_out;
  char*  ws  = (char*)d_ws;

  float* xz   = (float*)(ws + XZ_OFF);
  u16*   ub   = (u16*)(ws + UB_OFF);
  u16*   wt   = (u16*)(ws + WT_OFF);
  u32*   hbuf = (u32*)(ws + HB_OFF);

  hipMemsetAsync(hbuf, 0, HB_BYTES, stream);   // tag-0 init (safety proof in round 6)
  pack_w<<<2048, 64, 0, stream>>>(W, wt);
  pack_u<<<2048, 64, 0, stream>>>(U, ub);
  xz_gemm<<<8192, 256, 82560, stream>>>(tokens, emb, wt, bias, xz);
  lstm_persist<<<NWG, 512, 163840, stream>>>(xz, ub, hbuf, out);
}

// Round 11
// 1762.234 us; speedup vs baseline: 1.7340x; 1.7340x over previous
//
#include <hip/hip_runtime.h>
#include <hip/hip_bf16.h>

typedef unsigned short u16;
typedef unsigned int u32;
typedef unsigned long long u64;
typedef short  s16x8 __attribute__((ext_vector_type(8)));
typedef float  f32x4 __attribute__((ext_vector_type(4)));
typedef u32    u32x4 __attribute__((ext_vector_type(4)));

#define T_STEPS 512
#define BATCH   32
#define HID     512
#define EMBD    300
#define NGATE   2048

// ---- workspace layout (bytes) ----
#define XZ_OFF   0ull
#define XZ_BYTES (512ull*32*2048*4)          // 134,217,728  f32 [t][b][wg32][g][16]
#define UB_OFF   (XZ_OFF + XZ_BYTES)
#define UB_BYTES (2048ull*512*2)             // U bf16 [col][k] linear (per-lane reg fragments)
#define WT_OFF   (UB_OFF + UB_BYTES)
#define WT_BYTES (2048ull*320*2)             // W^T bf16 swizzled
#define HB_OFF   (WT_OFF + WT_BYTES)
#define HB_BYTES (2ull*8192*4)               // 2 slots x 8192 u32 of LSB-tagged bf16 pairs

__device__ inline u16 f2b(float f) {
  u32 u = __builtin_bit_cast(u32, f);
  return (u16)((u + 0x7fffu + ((u >> 16) & 1u)) >> 16);
}

__device__ inline void st64_agent(u64* p, u64 v) {
  __hip_atomic_store(p, v, __ATOMIC_RELAXED, __HIP_MEMORY_SCOPE_AGENT);
}

// ---------- pack W: [300][2048] f32 -> wt[n][kpad=320] bf16 swizzled ----------
__global__ __launch_bounds__(64) void pack_w(const float* __restrict__ W, u16* __restrict__ wt) {
  int n = blockIdx.x;
  for (int i = 0; i < 5; ++i) {
    int k = i * 64 + threadIdx.x;
    float v = (k < EMBD) ? W[(size_t)k * NGATE + n] : 0.f;
    u32 off = ((u32)(2 * k)) ^ (((u32)(n & 7)) << 4);
    *(u16*)((char*)wt + (size_t)n * 640 + off) = f2b(v);
  }
}

// ---------- pack U: [col][k] bf16 linear; col = wg*64 + nl, gate g = nl&3, j = wg*16+(nl>>2) ----
__global__ __launch_bounds__(64) void pack_u(const float* __restrict__ U, u16* __restrict__ ub) {
  int blk = blockIdx.x;             // = wg*64 + nl
  int w = blk >> 6, nl = blk & 63;
  int gcol = (nl & 3) * 512 + w * 16 + (nl >> 2);
  for (int i = 0; i < 8; ++i) {
    int k = i * 64 + threadIdx.x;
    float v = U[(size_t)k * NGATE + gcol];
    *(u16*)((char*)ub + (size_t)blk * 1024 + 2 * k) = f2b(v);
  }
}

// ---------- phase 1: xz = emb[tok] @ W + bias, layout [t][b][wg32][g][16] ----------
__global__ __launch_bounds__(256) void xz_gemm(const int* __restrict__ tokens,
                                               const float* __restrict__ emb,
                                               const u16* __restrict__ wt,
                                               const float* __restrict__ bias,
                                               float* __restrict__ xz) {
  extern __shared__ char smem[];
  const int tid = threadIdx.x;
  const int lane = tid & 63, wv = tid >> 6;
  const int m0 = (blockIdx.x >> 5) * 64;
  const int n0 = (blockIdx.x & 31) * 64;

  { // stage A: 64 emb rows gathered, f32 -> bf16
    int row = tid >> 2, q = tid & 3;
    int tok = tokens[m0 + row];
    const float* er = emb + (size_t)tok * EMBD;
    for (int i = 0; i < 10; ++i) {
      int k = q * 80 + i * 8;
      float4 lo = {0, 0, 0, 0}, hi = {0, 0, 0, 0};
      if (k <= 296) lo = *(const float4*)(er + k);
      if (k <= 292) hi = *(const float4*)(er + k + 4);
      u16 u[8] = {f2b(lo.x), f2b(lo.y), f2b(lo.z), f2b(lo.w),
                  f2b(hi.x), f2b(hi.y), f2b(hi.z), f2b(hi.w)};
      int kc = q * 10 + i;
      *(uint4*)(smem + kc * 1040 + row * 16) = *(uint4*)u;
    }
  }
  { // stage B: linear copy of pre-swizzled wt panel
    const uint4* src = (const uint4*)((const char*)wt + (size_t)n0 * 640);
    for (int i = 0; i < 10; ++i)
      *(uint4*)(smem + 41600 + (i * 256 + tid) * 16) = src[i * 256 + tid];
  }
  __syncthreads();

  const int mq = wv >> 1, nq = wv & 1;
  const int arow = lane & 15, kq4 = lane >> 4;
  f32x4 acc[2][2] = {};
#pragma unroll
  for (int ks = 0; ks < 10; ++ks) {
    s16x8 af[2], bfr[2];
#pragma unroll
    for (int mt = 0; mt < 2; ++mt) {
      int row = mq * 32 + mt * 16 + arow;
      int kc = ks * 4 + kq4;
      af[mt] = *(const s16x8*)(smem + kc * 1040 + row * 16);
    }
#pragma unroll
    for (int nt = 0; nt < 2; ++nt) {
      int nl = nq * 32 + nt * 16 + arow;
      u32 kb = (u32)(ks * 64 + (kq4 << 4));
      bfr[nt] = *(const s16x8*)(smem + 41600 + nl * 640 + (kb ^ (((u32)(nl & 7)) << 4)));
    }
#pragma unroll
    for (int mt = 0; mt < 2; ++mt)
#pragma unroll
      for (int nt = 0; nt < 2; ++nt)
        acc[mt][nt] = __builtin_amdgcn_mfma_f32_16x16x32_bf16(af[mt], bfr[nt], acc[mt][nt], 0, 0, 0);
  }
#pragma unroll
  for (int mt = 0; mt < 2; ++mt)
#pragma unroll
    for (int nt = 0; nt < 2; ++nt) {
      int gn = n0 + nq * 32 + nt * 16 + arow;
      float bv = bias[gn];
      int g = gn >> 9, j = gn & 511;
      size_t inner = (size_t)((j >> 4) * 64 + g * 16 + (j & 15));
#pragma unroll
      for (int r = 0; r < 4; ++r) {
        int gm = m0 + mq * 32 + mt * 16 + (kq4 << 2) + r;
        int tt = gm & 511, bb = gm >> 9;       // tokens flat = b*T + t
        xz[(size_t)(tt * 32 + bb) * 2048 + inner] = acc[mt][nt][r] + bv;
      }
    }
}

// ---------- phase 2: persistent 32-WG recurrent kernel ----------
// r7 structure + U held in VGPRs (16 statically-indexed s16x8 per lane; no U LDS)
// + publish coalesced to u64 (one store per 2 threads via shfl_xor(32)).
// Swapped-operand MFMA: lane (wv,kq,arow) holds all 4 gates of cells (b=arow,
// j=wg*16+4wv+kq) in acc0 and (b=arow+16) in acc1. Sync: LSB-embedded 2-bit tags.
__global__ __launch_bounds__(256) void lstm_persist(const float* __restrict__ xz,
                                                    const u16* __restrict__ ub,
                                                    u32* __restrict__ hbuf,
                                                    float* __restrict__ out) {
  extern __shared__ char smem[];
  char* hl = smem;                           // h tile [32][512] bf16 swizzled, 32KB
  const int tid = threadIdx.x;
  const int lane = tid & 63, wv = tid >> 6;
  const int wg = blockIdx.x;

  const int arow = lane & 15, kq = lane >> 4;
  const int nl = wv * 16 + arow;             // this wave's 16 gate-cols
  const u32 aswz = ((u32)(arow & 7)) << 4;
  const int j0 = wg * 16;
  const int jl = 4 * wv + kq;                // this lane's h-col (0..15)
  float c0 = 0.f, c1 = 0.f;                  // cell state: (b=arow, j0+jl), (b=arow+16, j0+jl)

  // U fragments in registers (loop-invariant): col nl, k = ks*32 + kq*8 .. +8
  s16x8 ureg[16];
  {
    const char* up = (const char*)ub + (size_t)(wg * 64 + nl) * 1024 + (kq << 4);
#pragma unroll
    for (int ks = 0; ks < 16; ++ks) ureg[ks] = *(const s16x8*)(up + ks * 64);
  }

  // poll address bases: thread covers u32 idx = tid*4 + l*1024, l=0..7
  const u32 vo0 = (u32)(tid * 16 + 1 * 4096), vo1 = (u32)(tid * 16 + 3 * 4096);
  const u32 vo2 = (u32)(tid * 16 + 5 * 4096), vo3 = (u32)(tid * 16 + 7 * 4096);
  const u32 hrow0 = (u32)(tid >> 6);
  const u32 hcolb = (u32)((tid & 63) * 16);

  // publish slot (constant): word idx = pb*256 + wg*8 + 2wv + (kq>>1); u64 idx /2
  const int pb   = (kq & 1) ? (arow + 16) : arow;
  const u32 pidx64 = (u32)(pb * 128 + wg * 4 + wv);

  float xzv[2][4];
  { // prefetch xz for t=0: [0][b][wg][g][jl]
    const float* p = xz + (size_t)arow * 2048 + wg * 64 + jl;
#pragma unroll
    for (int g = 0; g < 4; ++g) {
      xzv[0][g] = p[g * 16];
      xzv[1][g] = p[16 * 2048 + g * 16];
    }
  }
  __syncthreads();

  for (int t = 0; t < T_STEPS; ++t) {
    if (t > 0) {
      // ---- poll-copy h_t from MALL into LDS (tags embedded in bf16 LSBs) ----
      u32 tg = (((u32)t >> 1) + 1u) & 3u;
      u32 pat = (tg & 1u) | ((tg >> 1) << 16);
      const u64 sb = (u64)(uintptr_t)hbuf + (u64)((t & 1) * 32768);
      u32x4 q0, q1, q2, q3, q4, q5, q6, q7;
      int tries = 0;
      for (;;) {
        asm volatile(
          "global_load_dwordx4 %0, %8, %12 offset:-4096 sc0 sc1\n\t"
          "global_load_dwordx4 %1, %8, %12 sc0 sc1\n\t"
          "global_load_dwordx4 %2, %9, %12 offset:-4096 sc0 sc1\n\t"
          "global_load_dwordx4 %3, %9, %12 sc0 sc1\n\t"
          "global_load_dwordx4 %4, %10, %12 offset:-4096 sc0 sc1\n\t"
          "global_load_dwordx4 %5, %10, %12 sc0 sc1\n\t"
          "global_load_dwordx4 %6, %11, %12 offset:-4096 sc0 sc1\n\t"
          "global_load_dwordx4 %7, %11, %12 sc0 sc1\n\t"
          "s_waitcnt vmcnt(0)"
          : "=&v"(q0), "=&v"(q1), "=&v"(q2), "=&v"(q3),
            "=&v"(q4), "=&v"(q5), "=&v"(q6), "=&v"(q7)
          : "v"(vo0), "v"(vo1), "v"(vo2), "v"(vo3), "s"(sb)
          : "memory");
        u32 x0 = (q0.x ^ pat) | (q0.y ^ pat) | (q0.z ^ pat) | (q0.w ^ pat);
        u32 x1 = (q1.x ^ pat) | (q1.y ^ pat) | (q1.z ^ pat) | (q1.w ^ pat);
        u32 x2 = (q2.x ^ pat) | (q2.y ^ pat) | (q2.z ^ pat) | (q2.w ^ pat);
        u32 x3 = (q3.x ^ pat) | (q3.y ^ pat) | (q3.z ^ pat) | (q3.w ^ pat);
        u32 x4 = (q4.x ^ pat) | (q4.y ^ pat) | (q4.z ^ pat) | (q4.w ^ pat);
        u32 x5 = (q5.x ^ pat) | (q5.y ^ pat) | (q5.z ^ pat) | (q5.w ^ pat);
        u32 x6 = (q6.x ^ pat) | (q6.y ^ pat) | (q6.z ^ pat) | (q6.w ^ pat);
        u32 x7 = (q7.x ^ pat) | (q7.y ^ pat) | (q7.z ^ pat) | (q7.w ^ pat);
        u32 bad = (x0 | x1 | x2 | x3 | x4 | x5 | x6 | x7) & 0x00010001u;
        if (bad == 0 || ++tries > 65536) break;   // cap: fail loudly, never hang
        __builtin_amdgcn_s_sleep(1);
      }
#define HW(L, Q) { u32 r_ = hrow0 + 4u * (L);                                  \
        u32 off_ = r_ * 1024u + (hcolb ^ ((r_ & 7u) << 4));                    \
        *(u32x4*)(hl + off_) = (Q); }
      HW(0, q0) HW(1, q1) HW(2, q2) HW(3, q3)
      HW(4, q4) HW(5, q5) HW(6, q6) HW(7, q7)
#undef HW
    }
    __syncthreads();   // A: h_lds ready (poll success implies all prior reads done)

    f32x4 acc0 = {0, 0, 0, 0}, acc1 = {0, 0, 0, 0};
    if (t > 0) {  // z^T = U rows x h: rows=gate-cols, cols=batches; U from VGPRs
#pragma unroll
      for (int ks = 0; ks < 16; ++ks) {
        u32 kb = (u32)(ks * 64 + (kq << 4));
        s16x8 h0 = *(const s16x8*)(hl + arow * 1024 + (kb ^ aswz));
        s16x8 h1 = *(const s16x8*)(hl + (arow + 16) * 1024 + (kb ^ aswz));
        acc0 = __builtin_amdgcn_mfma_f32_16x16x32_bf16(ureg[ks], h0, acc0, 0, 0, 0);
        acc1 = __builtin_amdgcn_mfma_f32_16x16x32_bf16(ureg[ks], h1, acc1, 0, 0, 0);
      }
    }

    // gates in-register: acc0[g] = z[gate g][b=arow], acc1[g] = z[g][b=arow+16]
    float hov[2], cov[2];
#pragma unroll
    for (int e = 0; e < 2; ++e) {
      f32x4 zr = e ? acc1 : acc0;
      float zi = zr[0] + xzv[e][0];
      float zf = zr[1] + xzv[e][1];
      float zg = zr[2] + xzv[e][2];
      float zo = zr[3] + xzv[e][3];
      float ig = 1.f / (1.f + __expf(-zi));
      float fg = 1.f / (1.f + __expf(-zf));
      float gg = 1.f - 2.f / (__expf(2.f * zg) + 1.f);
      float og = 1.f / (1.f + __expf(-zo));
      float cc = e ? c1 : c0;
      cc = fg * cc + ig * gg;
      float hh = og * (1.f - 2.f / (__expf(2.f * cc) + 1.f));
      if (e) c1 = cc; else c0 = cc;
      hov[e] = hh; cov[e] = cc;
    }

    if (t < T_STEPS - 1) {
      // pair adjacent j across lanes kq^1 (shfl 16), then pair word-pairs across
      // kq^2 (shfl 32) -> one tagged u64 store per 2 threads.
      u32 pk = (u32)f2b(hov[0]) | ((u32)f2b(hov[1]) << 16);   // (b=arow | b=arow+16<<16)
      u32 pr = (u32)__shfl_xor((int)pk, 16, 64);              // partner j = jl^1
      u32 val = (kq & 1) ? ((pr >> 16) | (pk & 0xFFFF0000u))  // word for batch pb
                         : ((pk & 0xFFFFu) | (pr << 16));
      u32 tg2 = (((u32)(t + 1) >> 1) + 1u) & 3u;
      val = (val & 0xFFFEFFFEu) | (tg2 & 1u) | ((tg2 >> 1) << 16);
      u32 v2 = (u32)__shfl_xor((int)val, 32, 64);             // partner pair-word
      if (kq < 2) {
        u64 wide = (u64)val | ((u64)v2 << 32);
        st64_agent((u64*)(hbuf + (size_t)((t + 1) & 1) * 8192) + pidx64, wide);
      }
      { // prefetch next xz
        const float* p = xz + ((size_t)(t + 1) * 32 + arow) * 2048 + wg * 64 + jl;
#pragma unroll
        for (int g = 0; g < 4; ++g) {
          xzv[0][g] = p[g * 16];
          xzv[1][g] = p[16 * 2048 + g * 16];
        }
      }
    } else {
      int j = j0 + jl;
      out[arow * 512 + j]                 = hov[0];
      out[(arow + 16) * 512 + j]          = hov[1];
      out[16384 + arow * 512 + j]         = cov[0];
      out[16384 + (arow + 16) * 512 + j]  = cov[1];
    }
    // no trailing barrier: next iteration's barrier A orders hl overwrites, and a
    // WG's poll can't succeed until ALL waves of ALL WGs have published (which
    // happens only after their hl reads completed).
  }
}

extern "C" void kernel_launch(void* const* d_in, const int* in_sizes, int n_in,
                              void* d_out, int out_size, void* d_ws, size_t ws_size,
                              hipStream_t stream) {
  const int*   tokens = (const int*)d_in[0];
  const float* emb    = (const float*)d_in[1];
  const float* W      = (const float*)d_in[2];
  const float* U      = (const float*)d_in[3];
  const float* bias   = (const float*)d_in[4];
  float* out = (float*)d_out;
  char*  ws  = (char*)d_ws;

  float* xz   = (float*)(ws + XZ_OFF);
  u16*   ub   = (u16*)(ws + UB_OFF);
  u16*   wt   = (u16*)(ws + WT_OFF);
  u32*   hbuf = (u32*)(ws + HB_OFF);

  hipMemsetAsync(hbuf, 0, HB_BYTES, stream);   // tag-0 init (safety proof in round 6)
  pack_w<<<2048, 64, 0, stream>>>(W, wt);
  pack_u<<<2048, 64, 0, stream>>>(U, ub);
  xz_gemm<<<8192, 256, 82560, stream>>>(tokens, emb, wt, bias, xz);
  lstm_persist<<<32, 256, 32768, stream>>>(xz, ub, hbuf, out);
}

// Round 12
// 1593.932 us; speedup vs baseline: 1.9170x; 1.1056x over previous
//
#include <hip/hip_runtime.h>
#include <hip/hip_bf16.h>

typedef unsigned short u16;
typedef unsigned int u32;
typedef unsigned long long u64;
typedef short  s16x8 __attribute__((ext_vector_type(8)));
typedef float  f32x4 __attribute__((ext_vector_type(4)));
typedef u32    u32x4 __attribute__((ext_vector_type(4)));

#define T_STEPS 512
#define BATCH   32
#define HID     512
#define EMBD    300
#define NGATE   2048

// ---- workspace layout (bytes) ----
#define XZ_OFF   0ull
#define XZ_BYTES (512ull*32*2048*4)          // 134,217,728  f32 [t][b][wg32][g][16]
#define UB_OFF   (XZ_OFF + XZ_BYTES)
#define UB_BYTES (2048ull*512*2)             // U bf16 [col][k] linear (per-lane reg fragments)
#define WT_OFF   (UB_OFF + UB_BYTES)
#define WT_BYTES (2048ull*320*2)             // W^T bf16 swizzled
#define HB_OFF   (WT_OFF + WT_BYTES)
#define HB_BYTES (2ull*8192*4)               // 2 slots x 8192 u32 of LSB-tagged bf16 pairs
#define CNT_OFF  (HB_OFF + HB_BYTES)
#define CNT_BYTES 1024ull                    // 256 per-t-pair GEMM-done counters

__device__ inline u16 f2b(float f) {
  u32 u = __builtin_bit_cast(u32, f);
  return (u16)((u + 0x7fffu + ((u >> 16) & 1u)) >> 16);
}

__device__ inline void st32_agent(u32* p, u32 v) {
  __hip_atomic_store(p, v, __ATOMIC_RELAXED, __HIP_MEMORY_SCOPE_AGENT);
}
__device__ inline void st64_agent(u64* p, u64 v) {
  __hip_atomic_store(p, v, __ATOMIC_RELAXED, __HIP_MEMORY_SCOPE_AGENT);
}
__device__ inline u32 ld32_agent(const u32* p) {
  return __hip_atomic_load(p, __ATOMIC_RELAXED, __HIP_MEMORY_SCOPE_AGENT);
}
__device__ inline float ldxz(const float* p) {           // MALL-coherent f32 load
  return __builtin_bit_cast(float, ld32_agent((const u32*)p));
}
__device__ inline void wait_pair(const u32* c) {          // xz t-pair readiness (32 n-blocks)
  int tries = 0;
  while (ld32_agent(c) < 32u) {
    if (++tries > (1 << 22)) break;                       // fail loudly, never hang
    __builtin_amdgcn_s_sleep(2);
  }
}

// ---------- pack W: [300][2048] f32 -> wt[n][kpad=320] bf16 swizzled ----------
__global__ __launch_bounds__(64) void pack_w(const float* __restrict__ W, u16* __restrict__ wt) {
  int n = blockIdx.x;
  for (int i = 0; i < 5; ++i) {
    int k = i * 64 + threadIdx.x;
    float v = (k < EMBD) ? W[(size_t)k * NGATE + n] : 0.f;
    u32 off = ((u32)(2 * k)) ^ (((u32)(n & 7)) << 4);
    *(u16*)((char*)wt + (size_t)n * 640 + off) = f2b(v);
  }
}

// ---------- pack U: [col][k] bf16 linear; col = wg*64 + nl, gate g = nl&3, j = wg*16+(nl>>2) ----
__global__ __launch_bounds__(64) void pack_u(const float* __restrict__ U, u16* __restrict__ ub) {
  int blk = blockIdx.x;             // = wg*64 + nl
  int w = blk >> 6, nl = blk & 63;
  int gcol = (nl & 3) * 512 + w * 16 + (nl >> 2);
  for (int i = 0; i < 8; ++i) {
    int k = i * 64 + threadIdx.x;
    float v = U[(size_t)k * NGATE + gcol];
    *(u16*)((char*)ub + (size_t)blk * 1024 + 2 * k) = f2b(v);
  }
}

// ---------- fused kernel: blocks 0-31 = persistent LSTM, blocks 32+ = xz GEMM ----------
// GEMM is t-major (m-tile = 2 timesteps x 32 batches) so early blocks produce early t.
// xz handoff: GEMM stores xz via agent atomics (MALL), vmcnt-drains, barriers, then one
// agent atomicAdd on cnt[tpair]; LSTM waits cnt[tpair]>=32 then agent-loads xz (r3 pattern).
// LSTM h-exchange: LSB-embedded 2-bit tags, unchanged from r11 (proven floor protocol).
__global__ __launch_bounds__(256) void fused_enc(const int* __restrict__ tokens,
                                                 const float* __restrict__ emb,
                                                 const u16* __restrict__ wt,
                                                 const float* __restrict__ bias,
                                                 const u16* __restrict__ ub,
                                                 float* __restrict__ xz,
                                                 u32* __restrict__ hbuf,
                                                 u32* __restrict__ cnt,
                                                 float* __restrict__ out) {
  extern __shared__ char smem[];
  const int tid = threadIdx.x;
  const int bid = blockIdx.x;
  const int lane = tid & 63, wv = tid >> 6;

  if (bid >= 32) {
    // ================= GEMM path =================
    const int gbid = bid - 32;
    const int mtile = gbid >> 5;               // 0..255, t-pair index
    const int n0 = (gbid & 31) * 64;
    const int t0 = mtile * 2;

    { // stage A: 64 rows = (2 t) x (32 b), gathered emb, f32 -> bf16
      int row = tid >> 2, q = tid & 3;
      int tok = tokens[(row & 31) * 512 + t0 + (row >> 5)];
      const float* er = emb + (size_t)tok * EMBD;
      for (int i = 0; i < 10; ++i) {
        int k = q * 80 + i * 8;
        float4 lo = {0, 0, 0, 0}, hi = {0, 0, 0, 0};
        if (k <= 296) lo = *(const float4*)(er + k);
        if (k <= 292) hi = *(const float4*)(er + k + 4);
        u16 u[8] = {f2b(lo.x), f2b(lo.y), f2b(lo.z), f2b(lo.w),
                    f2b(hi.x), f2b(hi.y), f2b(hi.z), f2b(hi.w)};
        int kc = q * 10 + i;
        *(uint4*)(smem + kc * 1040 + row * 16) = *(uint4*)u;
      }
    }
    { // stage B: linear copy of pre-swizzled wt panel
      const uint4* src = (const uint4*)((const char*)wt + (size_t)n0 * 640);
      for (int i = 0; i < 10; ++i)
        *(uint4*)(smem + 41600 + (i * 256 + tid) * 16) = src[i * 256 + tid];
    }
    __syncthreads();

    const int mq = wv >> 1, nq = wv & 1;
    const int arow = lane & 15, kq4 = lane >> 4;
    f32x4 acc[2][2] = {};
#pragma unroll
    for (int ks = 0; ks < 10; ++ks) {
      s16x8 af[2], bfr[2];
#pragma unroll
      for (int mt = 0; mt < 2; ++mt) {
        int row = mq * 32 + mt * 16 + arow;
        int kc = ks * 4 + kq4;
        af[mt] = *(const s16x8*)(smem + kc * 1040 + row * 16);
      }
#pragma unroll
      for (int nt = 0; nt < 2; ++nt) {
        int nl = nq * 32 + nt * 16 + arow;
        u32 kb = (u32)(ks * 64 + (kq4 << 4));
        bfr[nt] = *(const s16x8*)(smem + 41600 + nl * 640 + (kb ^ (((u32)(nl & 7)) << 4)));
      }
#pragma unroll
      for (int mt = 0; mt < 2; ++mt)
#pragma unroll
        for (int nt = 0; nt < 2; ++nt)
          acc[mt][nt] = __builtin_amdgcn_mfma_f32_16x16x32_bf16(af[mt], bfr[nt], acc[mt][nt], 0, 0, 0);
    }
#pragma unroll
    for (int mt = 0; mt < 2; ++mt)
#pragma unroll
      for (int nt = 0; nt < 2; ++nt) {
        int gn = n0 + nq * 32 + nt * 16 + arow;
        float bv = bias[gn];
        int g = gn >> 9, j = gn & 511;
        size_t inner = (size_t)((j >> 4) * 64 + g * 16 + (j & 15));
#pragma unroll
        for (int r = 0; r < 4; ++r) {
          int lr = mq * 32 + mt * 16 + (kq4 << 2) + r;
          int tt = t0 + (lr >> 5), bb = lr & 31;
          float v = acc[mt][nt][r] + bv;
          st32_agent((u32*)xz + (size_t)(tt * 32 + bb) * 2048 + inner,
                     __builtin_bit_cast(u32, v));
        }
      }
    asm volatile("s_waitcnt vmcnt(0)" ::: "memory");   // all xz stores acked at MALL
    __syncthreads();                                   // every thread of the block done
    if (tid == 0)
      __hip_atomic_fetch_add(&cnt[mtile], 1u, __ATOMIC_RELAXED, __HIP_MEMORY_SCOPE_AGENT);
    return;
  }

  // ================= LSTM path (r11, unchanged protocol) =================
  char* hl = smem;                           // h tile [32][512] bf16 swizzled, 32KB
  const int wg = bid;

  const int arow = lane & 15, kq = lane >> 4;
  const int nl = wv * 16 + arow;             // this wave's 16 gate-cols
  const u32 aswz = ((u32)(arow & 7)) << 4;
  const int j0 = wg * 16;
  const int jl = 4 * wv + kq;                // this lane's h-col (0..15)
  float c0 = 0.f, c1 = 0.f;

  // U fragments in registers (loop-invariant): col nl, k = ks*32 + kq*8 .. +8
  s16x8 ureg[16];
  {
    const char* up = (const char*)ub + (size_t)(wg * 64 + nl) * 1024 + (kq << 4);
#pragma unroll
    for (int ks = 0; ks < 16; ++ks) ureg[ks] = *(const s16x8*)(up + ks * 64);
  }

  // poll address bases: thread covers u32 idx = tid*4 + l*1024, l=0..7
  const u32 vo0 = (u32)(tid * 16 + 1 * 4096), vo1 = (u32)(tid * 16 + 3 * 4096);
  const u32 vo2 = (u32)(tid * 16 + 5 * 4096), vo3 = (u32)(tid * 16 + 7 * 4096);
  const u32 hrow0 = (u32)(tid >> 6);
  const u32 hcolb = (u32)((tid & 63) * 16);

  // publish slot (constant): word idx = pb*256 + wg*8 + 2wv + (kq>>1); u64 idx /2
  const int pb   = (kq & 1) ? (arow + 16) : arow;
  const u32 pidx64 = (u32)(pb * 128 + wg * 4 + wv);

  float xzv[2][4];
  { // prefetch xz for t=0 (wait for GEMM t-pair 0, then MALL-coherent loads)
    wait_pair(&cnt[0]);
    const float* p = xz + (size_t)arow * 2048 + wg * 64 + jl;
#pragma unroll
    for (int g = 0; g < 4; ++g) {
      xzv[0][g] = ldxz(p + g * 16);
      xzv[1][g] = ldxz(p + 16 * 2048 + g * 16);
    }
  }
  __syncthreads();

  for (int t = 0; t < T_STEPS; ++t) {
    if (t > 0) {
      // ---- poll-copy h_t from MALL into LDS (tags embedded in bf16 LSBs) ----
      u32 tg = (((u32)t >> 1) + 1u) & 3u;
      u32 pat = (tg & 1u) | ((tg >> 1) << 16);
      const u64 sb = (u64)(uintptr_t)hbuf + (u64)((t & 1) * 32768);
      u32x4 q0, q1, q2, q3, q4, q5, q6, q7;
      int tries = 0;
      for (;;) {
        asm volatile(
          "global_load_dwordx4 %0, %8, %12 offset:-4096 sc0 sc1\n\t"
          "global_load_dwordx4 %1, %8, %12 sc0 sc1\n\t"
          "global_load_dwordx4 %2, %9, %12 offset:-4096 sc0 sc1\n\t"
          "global_load_dwordx4 %3, %9, %12 sc0 sc1\n\t"
          "global_load_dwordx4 %4, %10, %12 offset:-4096 sc0 sc1\n\t"
          "global_load_dwordx4 %5, %10, %12 sc0 sc1\n\t"
          "global_load_dwordx4 %6, %11, %12 offset:-4096 sc0 sc1\n\t"
          "global_load_dwordx4 %7, %11, %12 sc0 sc1\n\t"
          "s_waitcnt vmcnt(0)"
          : "=&v"(q0), "=&v"(q1), "=&v"(q2), "=&v"(q3),
            "=&v"(q4), "=&v"(q5), "=&v"(q6), "=&v"(q7)
          : "v"(vo0), "v"(vo1), "v"(vo2), "v"(vo3), "s"(sb)
          : "memory");
        u32 x0 = (q0.x ^ pat) | (q0.y ^ pat) | (q0.z ^ pat) | (q0.w ^ pat);
        u32 x1 = (q1.x ^ pat) | (q1.y ^ pat) | (q1.z ^ pat) | (q1.w ^ pat);
        u32 x2 = (q2.x ^ pat) | (q2.y ^ pat) | (q2.z ^ pat) | (q2.w ^ pat);
        u32 x3 = (q3.x ^ pat) | (q3.y ^ pat) | (q3.z ^ pat) | (q3.w ^ pat);
        u32 x4 = (q4.x ^ pat) | (q4.y ^ pat) | (q4.z ^ pat) | (q4.w ^ pat);
        u32 x5 = (q5.x ^ pat) | (q5.y ^ pat) | (q5.z ^ pat) | (q5.w ^ pat);
        u32 x6 = (q6.x ^ pat) | (q6.y ^ pat) | (q6.z ^ pat) | (q6.w ^ pat);
        u32 x7 = (q7.x ^ pat) | (q7.y ^ pat) | (q7.z ^ pat) | (q7.w ^ pat);
        u32 bad = (x0 | x1 | x2 | x3 | x4 | x5 | x6 | x7) & 0x00010001u;
        if (bad == 0 || ++tries > 65536) break;   // cap: fail loudly, never hang
        __builtin_amdgcn_s_sleep(1);
      }
#define HW(L, Q) { u32 r_ = hrow0 + 4u * (L);                                  \
        u32 off_ = r_ * 1024u + (hcolb ^ ((r_ & 7u) << 4));                    \
        *(u32x4*)(hl + off_) = (Q); }
      HW(0, q0) HW(1, q1) HW(2, q2) HW(3, q3)
      HW(4, q4) HW(5, q5) HW(6, q6) HW(7, q7)
#undef HW
    }
    __syncthreads();   // A: h_lds ready (poll success implies all prior reads done)

    f32x4 acc0 = {0, 0, 0, 0}, acc1 = {0, 0, 0, 0};
    if (t > 0) {  // z^T = U rows x h: rows=gate-cols, cols=batches; U from VGPRs
#pragma unroll
      for (int ks = 0; ks < 16; ++ks) {
        u32 kb = (u32)(ks * 64 + (kq << 4));
        s16x8 h0 = *(const s16x8*)(hl + arow * 1024 + (kb ^ aswz));
        s16x8 h1 = *(const s16x8*)(hl + (arow + 16) * 1024 + (kb ^ aswz));
        acc0 = __builtin_amdgcn_mfma_f32_16x16x32_bf16(ureg[ks], h0, acc0, 0, 0, 0);
        acc1 = __builtin_amdgcn_mfma_f32_16x16x32_bf16(ureg[ks], h1, acc1, 0, 0, 0);
      }
    }

    // gates in-register: acc0[g] = z[gate g][b=arow], acc1[g] = z[g][b=arow+16]
    float hov[2], cov[2];
#pragma unroll
    for (int e = 0; e < 2; ++e) {
      f32x4 zr = e ? acc1 : acc0;
      float zi = zr[0] + xzv[e][0];
      float zf = zr[1] + xzv[e][1];
      float zg = zr[2] + xzv[e][2];
      float zo = zr[3] + xzv[e][3];
      float ig = 1.f / (1.f + __expf(-zi));
      float fg = 1.f / (1.f + __expf(-zf));
      float gg = 1.f - 2.f / (__expf(2.f * zg) + 1.f);
      float og = 1.f / (1.f + __expf(-zo));
      float cc = e ? c1 : c0;
      cc = fg * cc + ig * gg;
      float hh = og * (1.f - 2.f / (__expf(2.f * cc) + 1.f));
      if (e) c1 = cc; else c0 = cc;
      hov[e] = hh; cov[e] = cc;
    }

    if (t < T_STEPS - 1) {
      // pair adjacent j across lanes kq^1 (shfl 16), then word-pairs across kq^2
      // (shfl 32) -> one tagged u64 store per 2 threads.
      u32 pk = (u32)f2b(hov[0]) | ((u32)f2b(hov[1]) << 16);
      u32 pr = (u32)__shfl_xor((int)pk, 16, 64);
      u32 val = (kq & 1) ? ((pr >> 16) | (pk & 0xFFFF0000u))
                         : ((pk & 0xFFFFu) | (pr << 16));
      u32 tg2 = (((u32)(t + 1) >> 1) + 1u) & 3u;
      val = (val & 0xFFFEFFFEu) | (tg2 & 1u) | ((tg2 >> 1) << 16);
      u32 v2 = (u32)__shfl_xor((int)val, 32, 64);
      if (kq < 2) {
        u64 wide = (u64)val | ((u64)v2 << 32);
        st64_agent((u64*)(hbuf + (size_t)((t + 1) & 1) * 8192) + pidx64, wide);
      }
      { // prefetch next xz (wait for its t-pair only on pair boundary)
        if (((t + 1) & 1) == 0) wait_pair(&cnt[(t + 1) >> 1]);
        const float* p = xz + ((size_t)(t + 1) * 32 + arow) * 2048 + wg * 64 + jl;
#pragma unroll
        for (int g = 0; g < 4; ++g) {
          xzv[0][g] = ldxz(p + g * 16);
          xzv[1][g] = ldxz(p + 16 * 2048 + g * 16);
        }
      }
    } else {
      int j = j0 + jl;
      out[arow * 512 + j]                 = hov[0];
      out[(arow + 16) * 512 + j]          = hov[1];
      out[16384 + arow * 512 + j]         = cov[0];
      out[16384 + (arow + 16) * 512 + j]  = cov[1];
    }
    // no trailing barrier: next iteration's barrier A orders hl overwrites, and a
    // WG's poll can't succeed until ALL waves of ALL WGs have published (which
    // happens only after their hl reads completed).
  }
}

extern "C" void kernel_launch(void* const* d_in, const int* in_sizes, int n_in,
                              void* d_out, int out_size, void* d_ws, size_t ws_size,
                              hipStream_t stream) {
  const int*   tokens = (const int*)d_in[0];
  const float* emb    = (const float*)d_in[1];
  const float* W      = (const float*)d_in[2];
  const float* U      = (const float*)d_in[3];
  const float* bias   = (const float*)d_in[4];
  float* out = (float*)d_out;
  char*  ws  = (char*)d_ws;

  float* xz   = (float*)(ws + XZ_OFF);
  u16*   ub   = (u16*)(ws + UB_OFF);
  u16*   wt   = (u16*)(ws + WT_OFF);
  u32*   hbuf = (u32*)(ws + HB_OFF);
  u32*   cnt  = (u32*)(ws + CNT_OFF);

  hipMemsetAsync(ws + HB_OFF, 0, HB_BYTES + CNT_BYTES, stream);  // tags + counters
  pack_w<<<2048, 64, 0, stream>>>(W, wt);
  pack_u<<<2048, 64, 0, stream>>>(U, ub);
  fused_enc<<<32 + 8192, 256, 82560, stream>>>(tokens, emb, wt, bias, ub,
                                               xz, hbuf, cnt, out);
}